// Round 7
// baseline (96.533 us; speedup 1.0000x reference)
//
#include <hip/hip_runtime.h>
#include <math.h>

#define NODES 4096
#define FEATS 256
#define BATCH 1024
#define LR_C 0.5f
#define SIGMA_C 70.4f

typedef _Float16 f16x8 __attribute__((ext_vector_type(8)));
typedef float floatx4 __attribute__((ext_vector_type(4)));

__device__ __forceinline__ void get_params(int it, float& lr, float& r2, float& i2r2) {
    float decay = __expf(-(float)it * (SIGMA_C / 100000.0f));
    float radius = SIGMA_C * decay + 1e-6f;
    lr = LR_C * decay;
    r2 = radius * radius;
    i2r2 = 1.0f / (2.0f * r2);
}

// monotone float -> uint key; u64 key = (fkey << 32) | idx (ties -> smaller idx)
__device__ __forceinline__ unsigned fkey(float f) {
    unsigned u = __float_as_uint(f);
    return (u & 0x80000000u) ? ~u : (u | 0x80000000u);
}
__device__ __forceinline__ unsigned long long shfl_xor_u64(unsigned long long v, int mask) {
    unsigned lo = (unsigned)v, hi = (unsigned)(v >> 32);
    lo = __shfl_xor(lo, mask, 64);
    hi = __shfl_xor(hi, mask, 64);
    return ((unsigned long long)hi << 32) | lo;
}

// ---- K1: fused GEMM1. Stages fp32 X/W -> fp16 hi/lo split in LDS, accumulates w2
//          in-loop, fp32-accurate sqd via 3-product split MFMA, per-row in-wave min
//          -> packed-u64 atomicMin(gmin). Tile 128b x 64n, grid (64, 8) = 512 blocks.
__global__ __launch_bounds__(256) void k_gemm1min(const float* __restrict__ X, const float* __restrict__ Wm,
                                                  unsigned long long* __restrict__ gmin) {
    __shared__ _Float16 Ah[128][40];
    __shared__ _Float16 Al[128][40];
    __shared__ _Float16 Bh[64][40];
    __shared__ _Float16 Bl[64][40];
    __shared__ float w2s[64];
    const int n0 = blockIdx.x * 64;
    const int b0 = blockIdx.y * 128;
    const int t = threadIdx.x;
    const int wave = t >> 6, lane = t & 63;
    const int lm = lane & 15, quad = lane >> 4;
    const int arow = t >> 1, ako = (t & 1) * 16;   // A: 128 rows x 2 threads (16 k each)
    const int brow = t >> 2, bko = (t & 3) * 8;    // B: 64 rows x 4 threads (8 k each)
    float w2p = 0.0f;
    floatx4 acc[2][4] = {};
    for (int k0 = 0; k0 < FEATS; k0 += 32) {
        {   // stage A (X rows), split hi/lo
            union { _Float16 h[16]; float4 q[2]; } uh, ul;
#pragma unroll
            for (int c = 0; c < 4; ++c) {
                float4 v = *(const float4*)&X[(size_t)(b0 + arow) * FEATS + k0 + ako + c * 4];
                _Float16 h0 = (_Float16)v.x, h1 = (_Float16)v.y, h2 = (_Float16)v.z, h3 = (_Float16)v.w;
                uh.h[c * 4 + 0] = h0; uh.h[c * 4 + 1] = h1; uh.h[c * 4 + 2] = h2; uh.h[c * 4 + 3] = h3;
                ul.h[c * 4 + 0] = (_Float16)(v.x - (float)h0);
                ul.h[c * 4 + 1] = (_Float16)(v.y - (float)h1);
                ul.h[c * 4 + 2] = (_Float16)(v.z - (float)h2);
                ul.h[c * 4 + 3] = (_Float16)(v.w - (float)h3);
            }
            *(float4*)&Ah[arow][ako] = uh.q[0];
            *(float4*)&Ah[arow][ako + 8] = uh.q[1];
            *(float4*)&Al[arow][ako] = ul.q[0];
            *(float4*)&Al[arow][ako + 8] = ul.q[1];
        }
        {   // stage B (W rows), split hi/lo + w2 partial
            union { _Float16 h[8]; float4 q; } uh, ul;
#pragma unroll
            for (int c = 0; c < 2; ++c) {
                float4 v = *(const float4*)&Wm[(size_t)(n0 + brow) * FEATS + k0 + bko + c * 4];
                w2p += v.x * v.x + v.y * v.y + v.z * v.z + v.w * v.w;
                _Float16 h0 = (_Float16)v.x, h1 = (_Float16)v.y, h2 = (_Float16)v.z, h3 = (_Float16)v.w;
                uh.h[c * 4 + 0] = h0; uh.h[c * 4 + 1] = h1; uh.h[c * 4 + 2] = h2; uh.h[c * 4 + 3] = h3;
                ul.h[c * 4 + 0] = (_Float16)(v.x - (float)h0);
                ul.h[c * 4 + 1] = (_Float16)(v.y - (float)h1);
                ul.h[c * 4 + 2] = (_Float16)(v.z - (float)h2);
                ul.h[c * 4 + 3] = (_Float16)(v.w - (float)h3);
            }
            *(float4*)&Bh[brow][bko] = uh.q;
            *(float4*)&Bl[brow][bko] = ul.q;
        }
        __syncthreads();
        f16x8 ah[2], al[2], bh[4], bl[4];
#pragma unroll
        for (int i = 0; i < 2; ++i) {
            ah[i] = *(f16x8*)&Ah[wave * 32 + i * 16 + lm][quad * 8];
            al[i] = *(f16x8*)&Al[wave * 32 + i * 16 + lm][quad * 8];
        }
#pragma unroll
        for (int j = 0; j < 4; ++j) {
            bh[j] = *(f16x8*)&Bh[j * 16 + lm][quad * 8];
            bl[j] = *(f16x8*)&Bl[j * 16 + lm][quad * 8];
        }
#pragma unroll
        for (int i = 0; i < 2; ++i)
#pragma unroll
            for (int j = 0; j < 4; ++j) {
                acc[i][j] = __builtin_amdgcn_mfma_f32_16x16x32_f16(ah[i], bh[j], acc[i][j], 0, 0, 0);
                acc[i][j] = __builtin_amdgcn_mfma_f32_16x16x32_f16(ah[i], bl[j], acc[i][j], 0, 0, 0);
                acc[i][j] = __builtin_amdgcn_mfma_f32_16x16x32_f16(al[i], bh[j], acc[i][j], 0, 0, 0);
            }
        __syncthreads();
    }
    // w2[brow]: 4 threads per row hold disjoint k-stripe partials (consecutive lanes)
    w2p += __shfl_xor(w2p, 1, 64);
    w2p += __shfl_xor(w2p, 2, 64);
    if ((t & 3) == 0) w2s[brow] = w2p;
    __syncthreads();
#pragma unroll
    for (int i = 0; i < 2; ++i)
#pragma unroll
        for (int r = 0; r < 4; ++r) {
            const int row = b0 + wave * 32 + i * 16 + quad * 4 + r;
            unsigned long long m = 0xFFFFFFFFFFFFFFFFULL;
#pragma unroll
            for (int j = 0; j < 4; ++j) {
                float v = w2s[j * 16 + lm] - 2.0f * acc[i][j][r];
                unsigned long long k = ((unsigned long long)fkey(v) << 32) | (unsigned)(n0 + j * 16 + lm);
                if (k < m) m = k;
            }
#pragma unroll
            for (int mk = 1; mk < 16; mk <<= 1) {  // reduce over lm (stays within quad group)
                unsigned long long o = shfl_xor_u64(m, mk);
                if (o < m) m = o;
            }
            if (lm == 0) atomicMin(&gmin[row], m);
        }
}

// ---- K2: blocks 0..2047: lr_op^T fp16 + Svec (+out1 from blocks 0..3);
//          blocks 2048..2111: XT build (X fp32 -> fp16 d-major transpose).
__global__ __launch_bounds__(256) void k_lropX(const unsigned long long* __restrict__ gmin,
                                               const int* __restrict__ itp, const float* __restrict__ X,
                                               _Float16* __restrict__ lrT, float* __restrict__ Svec,
                                               _Float16* __restrict__ XT, float* __restrict__ out1) {
    const int blk = blockIdx.x;
    const int t = threadIdx.x;
    if (blk < 2048) {
        __shared__ int bmu_s[1024];
        __shared__ float texp[64];
        __shared__ float red4[4];
#pragma unroll
        for (int j = 0; j < 4; ++j)
            bmu_s[t + j * 256] = (int)(gmin[t + j * 256] & 0xFFFFFFFFULL);
        float lr, r2, i2r2;
        get_params(itp[0], lr, r2, i2r2);
        if (t < 64) texp[t] = __expf(-(float)(t * t) * i2r2);
        __syncthreads();
        if (blk < 4) out1[blk * 256 + t] = (float)bmu_s[blk * 256 + t];
        const int n = blk * 2 + (t >> 7);
        const int b0 = (t & 127) * 8;
        const int ni = n >> 6, nj = n & 63;
        float s = 0.0f;
        union { _Float16 h[8]; float4 q; } u;
#pragma unroll
        for (int c = 0; c < 8; ++c) {
            int m = bmu_s[b0 + c];
            int di = ni - (m >> 6); di = di < 0 ? -di : di;
            int dj = nj - (m & 63); dj = dj < 0 ? -dj : dj;
            int d2 = di * di + dj * dj;
            float val = ((float)d2 <= r2) ? lr * texp[di] * texp[dj] : 0.0f;
            u.h[c] = (_Float16)val;
            s += val;
        }
        *(float4*)&lrT[(size_t)n * BATCH + b0] = u.q;
        const int lane = t & 63, wave = t >> 6;
#pragma unroll
        for (int off = 32; off > 0; off >>= 1) s += __shfl_down(s, off, 64);
        if (lane == 0) red4[wave] = s;
        __syncthreads();
        if (t < 2) Svec[blk * 2 + t] = red4[2 * t] + red4[2 * t + 1];
    } else {
        __shared__ _Float16 T[64][72];
        const int blk2 = blk - 2048;
        const int b0 = (blk2 & 15) * 64, d0 = (blk2 >> 4) * 64;
        {
            const int bl = t >> 2, dq = (t & 3) * 16;
            union { _Float16 h[16]; } u;
#pragma unroll
            for (int c = 0; c < 4; ++c) {
                float4 v = *(const float4*)&X[(size_t)(b0 + bl) * FEATS + d0 + dq + c * 4];
                u.h[c * 4 + 0] = (_Float16)v.x; u.h[c * 4 + 1] = (_Float16)v.y;
                u.h[c * 4 + 2] = (_Float16)v.z; u.h[c * 4 + 3] = (_Float16)v.w;
            }
#pragma unroll
            for (int c = 0; c < 16; ++c) T[bl][dq + c] = u.h[c];
        }
        __syncthreads();
        {
            const int dl = t >> 2, bq = (t & 3) * 16;
            union { _Float16 h[16]; float4 q[2]; } u;
#pragma unroll
            for (int c = 0; c < 16; ++c) u.h[c] = T[bq + c][dl];
            *(float4*)&XT[(size_t)(d0 + dl) * BATCH + b0 + bq] = u.q[0];
            *(float4*)&XT[(size_t)(d0 + dl) * BATCH + b0 + bq + 8] = u.q[1];
        }
    }
}

// ---- K3: fp16-MFMA GEMM (lr_op^T @ x), 32n x 64d tile, BK=128 (8 MFMA/barrier),
//          fused combine epilogue: out0 = Wm*(1 - Svec/B) + acc/B.
__global__ __launch_bounds__(256) void k_gemm2c(const _Float16* __restrict__ lrT, const _Float16* __restrict__ XT,
                                                const float* __restrict__ Svec, const float* __restrict__ Wm,
                                                float* __restrict__ out0) {
    __shared__ _Float16 As[32][136];
    __shared__ _Float16 Bs[64][136];
    __shared__ float Svl[32];
    const int d0 = blockIdx.x * 64;
    const int n0 = blockIdx.y * 32;
    const int t = threadIdx.x;
    const int wave = t >> 6, lane = t & 63;
    const int wm = wave & 1, wn = wave >> 1;
    const int lm = lane & 15, quad = lane >> 4;
    if (t < 32) Svl[t] = Svec[n0 + t];
    const int arow = t >> 3, acoff = (t & 7) * 16;
    const int brow = t >> 2, bcoff = (t & 3) * 32;
    floatx4 acc0 = {}, acc1 = {};
    for (int k0 = 0; k0 < BATCH; k0 += 128) {
        *(float4*)&As[arow][acoff] = *(const float4*)&lrT[(size_t)(n0 + arow) * BATCH + k0 + acoff];
        *(float4*)&As[arow][acoff + 8] = *(const float4*)&lrT[(size_t)(n0 + arow) * BATCH + k0 + acoff + 8];
#pragma unroll
        for (int c = 0; c < 4; ++c)
            *(float4*)&Bs[brow][bcoff + c * 8] =
                *(const float4*)&XT[(size_t)(d0 + brow) * BATCH + k0 + bcoff + c * 8];
        __syncthreads();
#pragma unroll
        for (int ks = 0; ks < 128; ks += 32) {
            f16x8 a = *(f16x8*)&As[wm * 16 + lm][ks + quad * 8];
            f16x8 b0 = *(f16x8*)&Bs[wn * 32 + lm][ks + quad * 8];
            f16x8 b1 = *(f16x8*)&Bs[wn * 32 + 16 + lm][ks + quad * 8];
            acc0 = __builtin_amdgcn_mfma_f32_16x16x32_f16(a, b0, acc0, 0, 0, 0);
            acc1 = __builtin_amdgcn_mfma_f32_16x16x32_f16(a, b1, acc1, 0, 0, 0);
        }
        __syncthreads();
    }
    const float invB = 1.0f / (float)BATCH;
#pragma unroll
    for (int r = 0; r < 4; ++r) {
        int rowN = n0 + wm * 16 + quad * 4 + r;
        float cc = 1.0f - Svl[rowN - n0] * invB;
        int col0 = d0 + wn * 32 + lm;
        int col1 = col0 + 16;
        out0[(size_t)rowN * FEATS + col0] = Wm[(size_t)rowN * FEATS + col0] * cc + acc0[r] * invB;
        out0[(size_t)rowN * FEATS + col1] = Wm[(size_t)rowN * FEATS + col1] * cc + acc1[r] * invB;
    }
}

extern "C" void kernel_launch(void* const* d_in, const int* in_sizes, int n_in,
                              void* d_out, int out_size, void* d_ws, size_t ws_size,
                              hipStream_t stream) {
    const float* X = (const float*)d_in[0];    // (1024, 256)
    const float* Wm = (const float*)d_in[1];   // (4096, 256)
    const int* itp = (const int*)d_in[2];      // scalar iteration
    float* out0 = (float*)d_out;
    float* out1 = out0 + (size_t)NODES * FEATS;

    char* ws = (char*)d_ws;
    unsigned long long* gmin = (unsigned long long*)(ws + 0);  // 8 KB
    float* Svec     = (float*)(ws + 8192);        // 16 KB
    _Float16* XT    = (_Float16*)(ws + 24576);    // 512 KB
    _Float16* lrT   = (_Float16*)(ws + 548864);   // 8 MB

    hipMemsetAsync(gmin, 0xFF, 1024 * sizeof(unsigned long long), stream);
    k_gemm1min<<<dim3(64, 8), 256, 0, stream>>>(X, Wm, gmin);
    k_lropX<<<2112, 256, 0, stream>>>(gmin, itp, X, lrT, Svec, XT, out1);
    k_gemm2c<<<dim3(4, 128), 256, 0, stream>>>(lrT, XT, Svec, Wm, out0);
}